// Round 1
// baseline (480.981 us; speedup 1.0000x reference)
//
#include <hip/hip_runtime.h>

// ImageMLP: y = softmax( actquant(x) @ ternquant(W)^T )
// x: [1024, 76800] f32, W: [8, 76800] f32, out: [1024, 8] f32
//
// Math: with sx = 127/clip(rowmax,EPS), q_i = clip(rintf(x_i*sx),-128,127) (int),
//       sw = 1/clip(mean|W|,EPS),      t_i = clip(rintf(w_i*sw),-1,1) (ternary),
//   y[b][o] = (sum_i q_i * t_oi) * clip(rowmax,EPS) * clip(mean|W|,EPS) / 127
// All q*t accumulation is integer-valued -> exact in f32.

constexpr int B_ROWS  = 1024;
constexpr int I_ELEMS = 76800;       // 3*160*160
constexpr int I_F4    = 19200;       // float4s per row
constexpr int O_OUT   = 8;
constexpr int W_N     = O_OUT * I_ELEMS;  // 614400
constexpr int W_F4    = W_N / 4;          // 153600
constexpr float EPS   = 1e-5f;

// ---------------------------------------------------------------- W |.| sum
__global__ __launch_bounds__(256) void k_wabs_sum(const float* __restrict__ W,
                                                  double* __restrict__ wsum) {
  int tid = blockIdx.x * blockDim.x + threadIdx.x;
  int stride = gridDim.x * blockDim.x;
  float s = 0.f;
  for (int f = tid; f < W_F4; f += stride) {
    float4 v = reinterpret_cast<const float4*>(W)[f];
    s += fabsf(v.x) + fabsf(v.y) + fabsf(v.z) + fabsf(v.w);
  }
  double d = (double)s;
  #pragma unroll
  for (int off = 32; off; off >>= 1) d += __shfl_xor(d, off);
  __shared__ double lds[4];
  int lane = threadIdx.x & 63;
  int wv   = threadIdx.x >> 6;
  if (lane == 0) lds[wv] = d;
  __syncthreads();
  if (threadIdx.x == 0) atomicAdd(wsum, lds[0] + lds[1] + lds[2] + lds[3]);
}

// ------------------------------------------------- pack ternary W as bytes
// codes layout: [o][f] dword, byte e = (int8)t[o][4f+e]  (same linear layout
// as W viewed as float4s, so index == tid)
__global__ __launch_bounds__(256) void k_pack(const float* __restrict__ W,
                                              const double* __restrict__ wsum,
                                              unsigned int* __restrict__ codes) {
  int tid = blockIdx.x * blockDim.x + threadIdx.x;
  if (tid >= W_F4) return;
  float meanc = fmaxf((float)(*wsum * (1.0 / (double)W_N)), EPS);
  float sw = 1.f / meanc;
  float4 v = reinterpret_cast<const float4*>(W)[tid];
  int b0 = (int)fminf(fmaxf(rintf(v.x * sw), -1.f), 1.f);
  int b1 = (int)fminf(fmaxf(rintf(v.y * sw), -1.f), 1.f);
  int b2 = (int)fminf(fmaxf(rintf(v.z * sw), -1.f), 1.f);
  int b3 = (int)fminf(fmaxf(rintf(v.w * sw), -1.f), 1.f);
  codes[tid] = (unsigned)(b0 & 0xff)        | ((unsigned)(b1 & 0xff) << 8) |
               ((unsigned)(b2 & 0xff) << 16) | ((unsigned)(b3 & 0xff) << 24);
}

// ----------------------------------------------------------------- fused main
// 512 blocks x 512 threads; each block does 2 rows sequentially.
// Working set in flight = 512 rows * 307 KB = 157 MB < 256 MB L3, and pass 2
// walks the row BACKWARD so the LRU-hottest bytes are re-read first.
__global__ __launch_bounds__(512) void k_main(const float* __restrict__ X,
                                              const unsigned int* __restrict__ codes,
                                              const double* __restrict__ wsum,
                                              float* __restrict__ out) {
  __shared__ float red[8];
  __shared__ float racc[8][8];
  const int t    = threadIdx.x;
  const int lane = t & 63;
  const int wv   = t >> 6;
  const float meanc = fmaxf((float)(*wsum * (1.0 / (double)W_N)), EPS);

  #pragma unroll 1
  for (int rr = 0; rr < 2; ++rr) {
    const int row = (blockIdx.x << 1) + rr;
    const float4* __restrict__ xrow =
        reinterpret_cast<const float4*>(X + (size_t)row * I_ELEMS);

    // ---- pass 1: row abs-max (forward stream)
    float m = 0.f;
    #pragma unroll 4
    for (int k = 0; k < 37; ++k) {
      float4 v = xrow[t + (k << 9)];
      m = fmaxf(m, fmaxf(fmaxf(fabsf(v.x), fabsf(v.y)),
                         fmaxf(fabsf(v.z), fabsf(v.w))));
    }
    if (t < 256) {   // tail: 19200 - 37*512 = 256 float4s
      float4 v = xrow[t + 18944];
      m = fmaxf(m, fmaxf(fmaxf(fabsf(v.x), fabsf(v.y)),
                         fmaxf(fabsf(v.z), fabsf(v.w))));
    }
    #pragma unroll
    for (int off = 32; off; off >>= 1) m = fmaxf(m, __shfl_xor(m, off));
    if (lane == 0) red[wv] = m;
    __syncthreads();
    float rowmax = red[0];
    #pragma unroll
    for (int i = 1; i < 8; ++i) rowmax = fmaxf(rowmax, red[i]);
    const float maxc = fmaxf(rowmax, EPS);
    const float sx = 127.f / maxc;

    // ---- pass 2: quantize + ternary dot (backward stream for L3 recency)
    float acc[8];
    #pragma unroll
    for (int o = 0; o < O_OUT; ++o) acc[o] = 0.f;

    auto body = [&](int f) {
      float4 v = xrow[f];
      float q0 = fminf(fmaxf(rintf(v.x * sx), -128.f), 127.f);
      float q1 = fminf(fmaxf(rintf(v.y * sx), -128.f), 127.f);
      float q2 = fminf(fmaxf(rintf(v.z * sx), -128.f), 127.f);
      float q3 = fminf(fmaxf(rintf(v.w * sx), -128.f), 127.f);
      #pragma unroll
      for (int o = 0; o < O_OUT; ++o) {
        unsigned w4 = codes[o * I_F4 + f];
        acc[o] += q0 * (float)((int)(w4 << 24) >> 24);
        acc[o] += q1 * (float)((int)(w4 << 16) >> 24);
        acc[o] += q2 * (float)((int)(w4 <<  8) >> 24);
        acc[o] += q3 * (float)((int)w4 >> 24);
      }
    };

    if (t < 256) body(t + 18944);           // tail first (it was loaded last)
    #pragma unroll 2
    for (int k = 36; k >= 0; --k) body(t + (k << 9));

    // ---- reduce 8 sums over 512 threads (integer-valued floats: exact)
    #pragma unroll
    for (int o = 0; o < O_OUT; ++o) {
      float a = acc[o];
      #pragma unroll
      for (int off = 32; off; off >>= 1) a += __shfl_xor(a, off);
      if (lane == 0) racc[wv][o] = a;
    }
    __syncthreads();

    if (t == 0) {
      const float fin = maxc * meanc * (1.f / 127.f);
      float y[8];
      #pragma unroll
      for (int o = 0; o < O_OUT; ++o)
        y[o] = (racc[0][o] + racc[1][o] + racc[2][o] + racc[3][o] +
                racc[4][o] + racc[5][o] + racc[6][o] + racc[7][o]) * fin;
      float mx = y[0];
      #pragma unroll
      for (int o = 1; o < O_OUT; ++o) mx = fmaxf(mx, y[o]);
      float e[8], s = 0.f;
      #pragma unroll
      for (int o = 0; o < O_OUT; ++o) { e[o] = expf(y[o] - mx); s += e[o]; }
      float inv = 1.f / s;
      #pragma unroll
      for (int o = 0; o < O_OUT; ++o) out[row * O_OUT + o] = e[o] * inv;
    }
    __syncthreads();  // red/racc reused next row
  }
}

// ------------------------------------------------------------------ launcher
extern "C" void kernel_launch(void* const* d_in, const int* in_sizes, int n_in,
                              void* d_out, int out_size, void* d_ws, size_t ws_size,
                              hipStream_t stream) {
  const float* X = (const float*)d_in[0];
  const float* W = (const float*)d_in[1];
  float* out = (float*)d_out;

  double* wsum = (double*)d_ws;                                  // 8 bytes
  unsigned int* codes = (unsigned int*)((char*)d_ws + 64);       // 614400 bytes

  hipMemsetAsync(d_ws, 0, 8, stream);                            // zero wsum
  k_wabs_sum<<<256, 256, 0, stream>>>(W, wsum);
  k_pack<<<(W_F4 + 255) / 256, 256, 0, stream>>>(W, wsum, codes);
  k_main<<<B_ROWS / 2, 512, 0, stream>>>(X, codes, wsum, out);
}